// Round 1
// 202.862 us; speedup vs baseline: 1.0041x; 1.0041x over previous
//
#include <hip/hip_runtime.h>

// LearnedClassVectors: bucketize fp32 volume into 10 HU bins, gather (10,12)
// embedding, re-tile into 4x4x4 patches -> out (B=2, 768, 32, 32, 32) fp32.
//
// R4: pw-split for 2x occupancy. Channel o = pc*48 + pw*12 + v and voxel
// (d,h,w) feeds only pw = w&3 — so splitting blocks by pw-pair partitions
// BOTH the output channels and the input voxels (no duplicated x traffic;
// the sibling half-block covers the other half of each 64B line, L3-shared).
// 2048 blocks * 4 waves = 32 waves/CU (hw max) vs R3's 16; every store
// depends on a 4-deep LDS-read chain, so the extra waves hide LDS latency
// and keep the HBM write drain saturated. Bins stay in registers (R3's
// barrier-free identity preserved); __launch_bounds__(256,8) caps VGPR<=64.

#define NTHREADS 256
#define NBLOCKS 2048  // 2 b * 32 gd * 16 p-chunks * 2 pw-halves

typedef float fx4 __attribute__((ext_vector_type(4)));
typedef float fx2 __attribute__((ext_vector_type(2)));

__global__ __launch_bounds__(NTHREADS, 8) void lcv_kernel(
    const float* __restrict__ x,
    const float* __restrict__ vectors,
    float* __restrict__ out)
{
    __shared__ float s_vec[120];

    const int tid = threadIdx.x;
    const int bid = blockIdx.x;
    const int hf  = bid >> 10;        // pw-half: this block owns pw = 2hf, 2hf+1
    const int b   = (bid >> 9) & 1;   // 2
    const int gd  = (bid >> 4) & 31;  // 32
    const int pc  = bid & 15;         // (pd,ph)
    const int pd  = pc >> 2, ph = pc & 3;

    if (tid < 120) s_vec[tid] = vectors[tid];

    // ---- Load this thread's 8 voxels: w = 16q + 4k + 2hf + {0,1}, k=0..3 ----
    // (exactly the voxels whose bins this thread's stores need: stored float
    //  c of fx4 tid at channel pw=2hf+jp is voxel w = 16q + 4c + 2hf + jp)
    const int row = tid >> 3;   // gh
    const int q   = tid & 7;
    const int d   = (gd << 2) + pd;
    const int h   = (row << 2) + ph;
    const fx2* xr = (const fx2*)(x + ((size_t)b << 21)
                  + (((d << 7) + h) << 7) + (q << 4) + (hf << 1));
    const fx2 xs0 = xr[0], xs1 = xr[2], xs2 = xr[4], xs3 = xr[6];

    __syncthreads();  // s_vec visible (only barrier; no bins round trip)

    // ---- Bins -> table row byte... word offsets, kept in registers ----
    // roff[j][k]: fx2 k (w-group 4k), component j (pw = 2hf+j): bin*12
    int roff[2][4];
    const fx2 xs[4] = {xs0, xs1, xs2, xs3};
    #pragma unroll
    for (int k = 0; k < 4; ++k) {
        #pragma unroll
        for (int j = 0; j < 2; ++j) {
            const float xx = xs[k][j];
            // searchsorted(side='right') == count(edges <= x)
            const int bin = (xx >= -1000.f) + (xx >= -75.f) + (xx >= 0.f)
                          + (xx >= 15.f)   + (xx >= 25.f)  + (xx >= 40.f)
                          + (xx >= 50.f)   + (xx >= 200.f) + (xx >= 1000.f);
            roff[j][k] = bin * 12;
        }
    }

    // ---- Stream 24 channels: o = pc*48 + (2hf+jp)*12 + v ----
    // thread t = float4 index within the (o, gd) row: 4 KB contiguous per o
    fx4* out4 = (fx4*)out
              + ((size_t)((b * 768 + pc * 48 + hf * 24) * 32 + gd) << 8) + tid;
    #pragma unroll
    for (int jp = 0; jp < 2; ++jp) {
        const int r0 = roff[jp][0], r1 = roff[jp][1];
        const int r2 = roff[jp][2], r3 = roff[jp][3];
        #pragma unroll
        for (int v = 0; v < 12; ++v) {
            fx4 r;
            r.x = s_vec[r0 + v];   // ds_read_b32, v*4 folded into offset imm
            r.y = s_vec[r1 + v];
            r.z = s_vec[r2 + v];
            r.w = s_vec[r3 + v];
            out4[(jp * 12 + v) * 8192] = r;
        }
    }
}

extern "C" void kernel_launch(void* const* d_in, const int* in_sizes, int n_in,
                              void* d_out, int out_size, void* d_ws, size_t ws_size,
                              hipStream_t stream) {
    const float* x       = (const float*)d_in[0];
    const float* vectors = (const float*)d_in[1];
    float* out           = (float*)d_out;
    lcv_kernel<<<NBLOCKS, NTHREADS, 0, stream>>>(x, vectors, out);
}